// Round 1
// baseline (290.688 us; speedup 1.0000x reference)
//
#include <hip/hip_runtime.h>

#define EPS 1e-5f
#define B 16
#define CH 22
#define T_IN 1001
#define F 36
#define RF 65
#define T1 937            // T_IN - RF + 1
#define TT 16             // K1 t-tile
#define NT 59             // ceil(937/16)
#define XS_W (TT + RF - 1) // 80
#define UN 885            // valid u range for Q/E
#define UT 64             // K2 u-tile
#define NU 14             // ceil(885/64)
#define PS_LEN 106        // UT-1 + 3*14 + 1
#define KS 15
#define GN 295
#define WN 129
#define M43 43

#define H2_OFF 0
#define E_OFF  539712     // 16*36*937
#define S_OFF  1049472    // E_OFF + 16*36*885

__device__ __forceinline__ float elu_f(float v) {
    return v > 0.f ? v : (__expf(v) - 1.f);
}

// ---------------- K1: temporal conv + bn + elu + spatial conv + bn + elu ----
__global__ __launch_bounds__(256) void k_front(
    const float* __restrict__ x,   const float* __restrict__ w_t,
    const float* __restrict__ b_t, const float* __restrict__ g_t,
    const float* __restrict__ be_t,const float* __restrict__ m_t,
    const float* __restrict__ v_t, const float* __restrict__ w_s,
    const float* __restrict__ b_s, const float* __restrict__ g_s,
    const float* __restrict__ be_s,const float* __restrict__ m_s,
    const float* __restrict__ v_s, float* __restrict__ h2)
{
    __shared__ float xs[CH * XS_W];     // 7.0 KB
    __shared__ float h1s[F * CH * TT];  // 50.7 KB
    __shared__ float wts[F * RF];       // 9.4 KB
    __shared__ float st[F], ot[F], ss[F], os[F];

    const int tid = threadIdx.x;
    const int b  = blockIdx.y;
    const int t0 = blockIdx.x * TT;

    for (int i = tid; i < CH * XS_W; i += 256) {
        int ch = i / XS_W, j = i % XS_W;
        int t = t0 + j;
        xs[i] = (t < T_IN) ? x[(b * CH + ch) * T_IN + t] : 0.f;
    }
    for (int i = tid; i < F * RF; i += 256) wts[i] = w_t[i];
    if (tid < F) {
        float s1 = g_t[tid] * rsqrtf(v_t[tid] + EPS);
        st[tid] = s1; ot[tid] = (b_t[tid] - m_t[tid]) * s1 + be_t[tid];
        float s2 = g_s[tid] * rsqrtf(v_s[tid] + EPS);
        ss[tid] = s2; os[tid] = (b_s[tid] - m_s[tid]) * s2 + be_s[tid];
    }
    __syncthreads();

    // temporal conv: items (fi, ch, t-half of 8), rolling register window
    for (int it = tid; it < F * CH * 2; it += 256) {
        int th = it & 1, fc = it >> 1;
        int ch = fc % CH, fi = fc / CH;
        const float* xr = &xs[ch * XS_W + th * 8];
        const float* wr = &wts[fi * RF];
        float xw[8], acc[8];
        #pragma unroll
        for (int j = 0; j < 8; ++j) { xw[j] = xr[j]; acc[j] = 0.f; }
        #pragma unroll
        for (int k = 0; k < RF; ++k) {
            float wv = wr[k];
            #pragma unroll
            for (int j = 0; j < 8; ++j) acc[j] += xw[j] * wv;
            if (k < RF - 1) {
                #pragma unroll
                for (int j = 0; j < 7; ++j) xw[j] = xw[j + 1];
                xw[7] = xr[k + 8];
            }
        }
        float sc = st[fi], of = ot[fi];
        #pragma unroll
        for (int j = 0; j < 8; ++j) {
            float v2 = acc[j] * sc + of;
            h1s[fc * TT + th * 8 + j] = elu_f(v2);
        }
    }
    __syncthreads();

    // spatial conv: thread = (t, fo-group); groups 0..3 carry a third fo
    {
        int t = tid & 15, fog = tid >> 4;        // fog in [0,16)
        int foA = fog * 2, foB = foA + 1;
        bool hasC = (fog < 4);
        int foC = hasC ? (32 + fog) : 35;        // clamped in-bounds
        const float* wA = w_s + foA * (F * CH);
        const float* wB = w_s + foB * (F * CH);
        const float* wC = w_s + foC * (F * CH);
        float aA = 0.f, aB = 0.f, aC = 0.f;
        #pragma unroll 4
        for (int fc = 0; fc < F * CH; ++fc) {
            float v = h1s[fc * TT + t];
            aA += v * wA[fc];
            aB += v * wB[fc];
            aC += v * wC[fc];
        }
        int t_g = t0 + t;
        if (t_g < T1) {
            float vA = elu_f(aA * ss[foA] + os[foA]);
            float vB = elu_f(aB * ss[foB] + os[foB]);
            h2[(b * F + foA) * T1 + t_g] = vA;
            h2[(b * F + foB) * T1 + t_g] = vB;
            if (hasC) {
                float vC = elu_f(aC * ss[foC] + os[foC]);
                h2[(b * F + foC) * T1 + t_g] = vC;
            }
        }
    }
}

// ---------------- K2: pooled dilated conv Q + bn + elu -> E -----------------
__global__ __launch_bounds__(256) void k_qconv(
    const float* __restrict__ h2, const float* __restrict__ w_c,
    const float* __restrict__ b_c, const float* __restrict__ g_c,
    const float* __restrict__ be_c, const float* __restrict__ m_c,
    const float* __restrict__ v_c, float* __restrict__ E)
{
    __shared__ float Ps[F * PS_LEN];   // 15.3 KB
    __shared__ float wcs[F * F * KS];  // 77.8 KB
    const int tid = threadIdx.x;
    const int b  = blockIdx.y;
    const int u0 = blockIdx.x * UT;

    for (int i = tid; i < F * F * KS; i += 256) wcs[i] = w_c[i];
    for (int i = tid; i < F * PS_LEN; i += 256) {
        int f = i / PS_LEN, j = i % PS_LEN;
        int s = u0 + j;
        const float* hr = h2 + (b * F + f) * T1;
        float a0 = (s     < T1) ? hr[s]     : 0.f;
        float a1 = (s + 1 < T1) ? hr[s + 1] : 0.f;
        float a2 = (s + 2 < T1) ? hr[s + 2] : 0.f;
        Ps[i] = (a0 + a1 + a2) * (1.f / 3.f);
    }
    __syncthreads();

    const int u = tid & 63, og = tid >> 6;  // og in [0,4), 9 fo each
    float acc[9];
    #pragma unroll
    for (int j = 0; j < 9; ++j) acc[j] = 0.f;

    for (int f = 0; f < F; ++f) {
        #pragma unroll
        for (int k = 0; k < KS; ++k) {
            float pv = Ps[f * PS_LEN + u + 3 * k];
            #pragma unroll
            for (int j = 0; j < 9; ++j)
                acc[j] += pv * wcs[((og * 9 + j) * F + f) * KS + k];
        }
    }
    int u_g = u0 + u;
    if (u_g < UN) {
        #pragma unroll
        for (int j = 0; j < 9; ++j) {
            int fo = og * 9 + j;
            float s  = g_c[fo] * rsqrtf(v_c[fo] + EPS);
            float v2 = (acc[j] + b_c[fo] - m_c[fo]) * s + be_c[fo];
            E[(b * F + fo) * UN + u_g] = elu_f(v2);
        }
    }
}

// ---------------- K3: crop-sum window sums -> S -----------------------------
__global__ __launch_bounds__(256) void k_wins(
    const float* __restrict__ E, float* __restrict__ S)
{
    __shared__ float Es[UN];
    __shared__ float G[GN];
    __shared__ float Ws[WN];
    const int tid = threadIdx.x;
    const int bf = blockIdx.x;
    const float* er = E + bf * UN;
    for (int i = tid; i < UN; i += 256) Es[i] = er[i];
    __syncthreads();
    for (int q = tid; q < GN; q += 256)
        G[q] = Es[3 * q] + Es[3 * q + 1] + Es[3 * q + 2];
    __syncthreads();
    if (tid < WN) {
        float a = 0.f;
        for (int q = tid; q < tid + 167; ++q) a += G[q];
        Ws[tid] = a;
    }
    __syncthreads();
    if (tid < M43)
        S[bf * M43 + tid] = (Ws[3 * tid] + Ws[3 * tid + 1] + Ws[3 * tid + 2]) * (1.f / 3.f);
}

// ---------------- K4: FC over summed features -------------------------------
__global__ __launch_bounds__(256) void k_fc(
    const float* __restrict__ S, const float* __restrict__ w_fc,
    const float* __restrict__ b_fc, float* __restrict__ out)
{
    const int b = blockIdx.x;
    const int o = threadIdx.x >> 6;
    const int lane = threadIdx.x & 63;
    float acc = 0.f;
    for (int n = lane; n < F * M43; n += 64)
        acc += w_fc[o * (F * M43) + n] * S[b * (F * M43) + n];
    #pragma unroll
    for (int off = 32; off > 0; off >>= 1)
        acc += __shfl_down(acc, off, 64);
    if (lane == 0) out[b * 4 + o] = acc * (1.f / 501.f) + b_fc[o];
}

extern "C" void kernel_launch(void* const* d_in, const int* in_sizes, int n_in,
                              void* d_out, int out_size, void* d_ws, size_t ws_size,
                              hipStream_t stream) {
    const float* x    = (const float*)d_in[0];
    const float* w_t  = (const float*)d_in[1];
    const float* b_t  = (const float*)d_in[2];
    const float* g_t  = (const float*)d_in[3];
    const float* be_t = (const float*)d_in[4];
    const float* m_t  = (const float*)d_in[5];
    const float* v_t  = (const float*)d_in[6];
    const float* w_s  = (const float*)d_in[7];
    const float* b_s  = (const float*)d_in[8];
    const float* g_s  = (const float*)d_in[9];
    const float* be_s = (const float*)d_in[10];
    const float* m_s  = (const float*)d_in[11];
    const float* v_s  = (const float*)d_in[12];
    const float* w_c  = (const float*)d_in[13];
    const float* b_c  = (const float*)d_in[14];
    const float* g_c  = (const float*)d_in[15];
    const float* be_c = (const float*)d_in[16];
    const float* m_c  = (const float*)d_in[17];
    const float* v_c  = (const float*)d_in[18];
    const float* w_fc = (const float*)d_in[19];
    const float* b_fc = (const float*)d_in[20];

    float* ws = (float*)d_ws;
    float* h2 = ws + H2_OFF;
    float* E  = ws + E_OFF;
    float* S  = ws + S_OFF;
    float* out = (float*)d_out;

    k_front<<<dim3(NT, B), 256, 0, stream>>>(x, w_t, b_t, g_t, be_t, m_t, v_t,
                                             w_s, b_s, g_s, be_s, m_s, v_s, h2);
    k_qconv<<<dim3(NU, B), 256, 0, stream>>>(h2, w_c, b_c, g_c, be_c, m_c, v_c, E);
    k_wins<<<B * F, 256, 0, stream>>>(E, S);
    k_fc<<<B, 256, 0, stream>>>(S, w_fc, b_fc, out);
}